// Round 4
// baseline (387.484 us; speedup 1.0000x reference)
//
#include <hip/hip_runtime.h>

// CompanionSSM, fully fused: one wave per head, zero barriers, one launch.
// Per head: G(128x128 bf16) = [[W, ToepK],[T, V]] built in-block (inlined prep),
// held entirely in VGPRs as 32 MFMA A-fragments. Per chunk q (C=64):
//   Z = G @ [S_q; U_q]   (8 row-tiles x 4 k-tiles, 32 MFMAs)
//   Z rows 0..63  -> Y chunk (scalar stores, L2-combined across the 8 heads
//                    sharing each 128B line; XCD swizzle keeps them on one L2)
//   Z rows 64..127-> S_{q+1}: C-layout -> bf16 -> wave-private LDS transpose
//                    -> next chunk's B-frags (the only serial dependency)
// U enters directly in B-frag register layout via 16 scalar loads, prefetched
// 2 chunks ahead (no barriers -> no vmcnt(0) drains on the critical path).

#define NKH 256
#define KD  64
#define SL  4096
#define DM  1024
#define NCHUNK 64

typedef __attribute__((ext_vector_type(8))) short short8;
typedef __attribute__((ext_vector_type(4))) float floatx4;

static __device__ __forceinline__ unsigned pack_bf16(float a, float b) {
  union { float f; unsigned u; } ua, ub;
  ua.f = a; ub.f = b;
  return __builtin_amdgcn_perm(ub.u + 0x8000u, ua.u + 0x8000u, 0x07060302u);
}
static __device__ __forceinline__ unsigned short f2bfru(float x) {
  union { float f; unsigned u; } v; v.f = x;
  return (unsigned short)((v.u + 0x8000u) >> 16);
}
static __device__ __forceinline__ float wredsum(float x) {
#pragma unroll
  for (int off = 32; off; off >>= 1) x += __shfl_xor(x, off, 64);
  return x;
}

__global__ __launch_bounds__(64, 1) void fused_kernel(
    const float* __restrict__ u, const float* __restrict__ ga,
    const float* __restrict__ gb, const float* __restrict__ gc,
    float* __restrict__ out)
{
  __shared__ unsigned short G[128 * 128];  // 32 KB, one head's G
  __shared__ float phi[128];
  __shared__ float kv[64];
  __shared__ unsigned short Xk[16 * 72];   // S transpose buf, stride 72 shorts

  const int i = blockIdx.x;
  // blocks i, i+32, ..., i+224 share i%8 (XCD id) -> give them heads 8g..8g+7,
  // which co-own every 128B line of u/y (cols 4h..4h+3).
  const int h = 8 * (i & 31) + (i >> 5);
  const int lane = threadIdx.x;
  const int n16 = lane & 15, quad = lane >> 4;

  // ---------------- inlined prep (single wave, lgkmcnt-ordered, no barriers)
  const float av = ga[h*KD + lane];
  const float an = av / wredsum(fabsf(av));   // mean(|rowsum|) >> eps, always normalize
  const float bv = gb[h*KD + lane];
  const float cv = gc[h*KD + lane];

  phi[lane] = cv;   // phi_p = c . A^p e0 ; for p<64, A^p e0 = e_p

  { // v-chain: v_j = A^j b -> V block G[64+i][64+m], m=63-j ; k[j] = c.v_j
    float v = bv;
    for (int j = 0; j < KD; ++j) {
      const float d = wredsum(cv * v);
      if (lane == 0) kv[j] = d;
      G[(64 + lane)*128 + 64 + (63 - j)] = f2bfru(v);
      const float top = __shfl(v, 63, 64);
      const float vm1 = __shfl_up(v, 1, 64);
      v = (lane > 0 ? vm1 : 0.0f) + an * top;
    }
  }
  { // g-chain: g_p = A^p e0, p=64..127 ; T col m = g_{64+m} ; phi_p = c.g_p
    float g = an;
    for (int p = 64; p < 128; ++p) {
      G[(64 + lane)*128 + (p - 64)] = f2bfru(g);
      const float d = wredsum(cv * g);
      if (lane == 0) phi[p] = d;
      const float top = __shfl(g, 63, 64);
      const float gm1 = __shfl_up(g, 1, 64);
      g = (lane > 0 ? gm1 : 0.0f) + an * top;
    }
  }
  // W block: G[j][i] = phi[j+1+i] ; Toeplitz: G[j][64+m] = (m<=j) ? k[j-m] : 0
  for (int j = 0; j < 64; ++j) G[j*128 + lane] = f2bfru(phi[j + 1 + lane]);
  for (int j = 0; j < 64; ++j)
    G[j*128 + 64 + lane] = (lane <= j) ? f2bfru(kv[j - lane]) : (unsigned short)0;

  // ---------------- all of G into A-fragment registers (128 VGPRs)
  short8 A[8][4];
#pragma unroll
  for (int rt = 0; rt < 8; ++rt)
#pragma unroll
    for (int kt = 0; kt < 4; ++kt)
      A[rt][kt] = *(const short8*)(G + (16*rt + n16)*128 + 32*kt + quad*8);

  // ---------------- scan
  short8 B0 = {0,0,0,0,0,0,0,0};   // S_0 = 0
  short8 B1 = {0,0,0,0,0,0,0,0};

  const size_t cs = (size_t)(n16 >> 2) * ((size_t)SL * DM) + 4*h + (n16 & 3);
  const float* up = u + cs;    // lane's column: batch = n16>>2, d = 4h + (n16&3)
  float*       op = out + cs;

  float ur[2][16];             // B-frag-layout u, 2-chunk prefetch pipeline
#pragma unroll
  for (int j = 0; j < 8; ++j) {
    ur[0][j]     = up[(size_t)(      quad*8 + j) * DM];
    ur[0][8 + j] = up[(size_t)(32 +  quad*8 + j) * DM];
    ur[1][j]     = up[(size_t)(64 +  quad*8 + j) * DM];
    ur[1][8 + j] = up[(size_t)(96 +  quad*8 + j) * DM];
  }

#pragma unroll 1
  for (int q = 0; q < NCHUNK; ++q) {
    // U B-frags from prefetched registers
    short8 B2, B3;
    {
      union { short8 v; unsigned s[4]; } b2, b3;
      const float* uq = ur[q & 1];
#pragma unroll
      for (int jj = 0; jj < 4; ++jj) {
        b2.s[jj] = pack_bf16(uq[2*jj],     uq[2*jj + 1]);
        b3.s[jj] = pack_bf16(uq[8 + 2*jj], uq[8 + 2*jj + 1]);
      }
      B2 = b2.v; B3 = b3.v;
    }
    // prefetch chunk q+2 (completes during ~2 chunk iterations; no barrier drains)
    if (q < NCHUNK - 2) {
      float* uq = ur[q & 1];
      const size_t r0 = (size_t)(q + 2) * 64;
#pragma unroll
      for (int j = 0; j < 8; ++j) {
        uq[j]     = up[(r0 +      quad*8 + j) * DM];
        uq[8 + j] = up[(r0 + 32 + quad*8 + j) * DM];
      }
    }

    // ---- S' tiles first: they are the serial dependency ----
    floatx4 accS[4];
#pragma unroll
    for (int rt = 0; rt < 4; ++rt) {
      floatx4 t = {0.f, 0.f, 0.f, 0.f};
      t = __builtin_amdgcn_mfma_f32_16x16x32_bf16(A[4+rt][0], B0, t, 0,0,0);
      t = __builtin_amdgcn_mfma_f32_16x16x32_bf16(A[4+rt][1], B1, t, 0,0,0);
      t = __builtin_amdgcn_mfma_f32_16x16x32_bf16(A[4+rt][2], B2, t, 0,0,0);
      accS[rt] = __builtin_amdgcn_mfma_f32_16x16x32_bf16(A[4+rt][3], B3, t, 0,0,0);
    }
    // C-layout -> bf16 -> LDS [col][row] -> next chunk's B-frags
#pragma unroll
    for (int rt = 0; rt < 4; ++rt) {
      uint2 pk;
      pk.x = pack_bf16(accS[rt][0], accS[rt][1]);
      pk.y = pack_bf16(accS[rt][2], accS[rt][3]);
      *(uint2*)((char*)Xk + 144*n16 + 32*rt + 8*quad) = pk;
    }
    const short8 nB0 = *(const short8*)((char*)Xk + 144*n16 + 16*quad);
    const short8 nB1 = *(const short8*)((char*)Xk + 144*n16 + 64 + 16*quad);

    // ---- Y tiles (use S_q = old B0,B1); overlap the LDS round-trip ----
#pragma unroll
    for (int rt = 0; rt < 4; ++rt) {
      floatx4 t = {0.f, 0.f, 0.f, 0.f};
      t = __builtin_amdgcn_mfma_f32_16x16x32_bf16(A[rt][0], B0, t, 0,0,0);
      t = __builtin_amdgcn_mfma_f32_16x16x32_bf16(A[rt][1], B1, t, 0,0,0);
      t = __builtin_amdgcn_mfma_f32_16x16x32_bf16(A[rt][2], B2, t, 0,0,0);
      t = __builtin_amdgcn_mfma_f32_16x16x32_bf16(A[rt][3], B3, t, 0,0,0);
      const size_t rbase = (size_t)(q*64 + 16*rt + 4*quad);
#pragma unroll
      for (int r = 0; r < 4; ++r) op[(rbase + r) * DM] = t[r];
    }

    B0 = nB0; B1 = nB1;
  }
}

// ---------------------------------------------------------------- launch --
extern "C" void kernel_launch(void* const* d_in, const int* in_sizes, int n_in,
                              void* d_out, int out_size, void* d_ws, size_t ws_size,
                              hipStream_t stream)
{
  const float* u = (const float*)d_in[0];
  const float* a = (const float*)d_in[1];
  const float* b = (const float*)d_in[2];
  const float* c = (const float*)d_in[3];
  float* out = (float*)d_out;
  (void)d_ws; (void)ws_size;

  fused_kernel<<<NKH, KD, 0, stream>>>(u, a, b, c, out);
}

// Round 5
// 194.398 us; speedup vs baseline: 1.9933x; 1.9933x over previous
//
#include <hip/hip_runtime.h>

// CompanionSSM, one launch: one block (8 waves, 512 thr) per head.
// G(128x128 bf16) = [[W, ToepK],[T, V]] built in LDS (prep), then split into
// per-wave register A-fragments. Sequence = 4 quarters x 16 chunks (C=64):
//   Phase A (8 waves): U -> register B-frags (kept for C), R=V@U -> LDS slots
//   Phase B (wave 0) : serial S'=T@S+R over 16 slots, slots <- S_q B-frags
//   Phase C (8 waves): Y = W@S + Toep@U, scalar C-layout stores
// LDS: 16 slots x 2KB (aliases dead prep-G) + transpose buf + phi/kv = 35KB.
// u read once (register U-frags), y written once (XCD swizzle => 65MB exact).

#define NKH 256
#define KD  64
#define SL  4096
#define DM  1024

typedef __attribute__((ext_vector_type(8))) short short8;
typedef __attribute__((ext_vector_type(4))) float floatx4;

static __device__ __forceinline__ unsigned pack_bf16(float a, float b) {
  union { float f; unsigned u; } ua, ub;
  ua.f = a; ub.f = b;
  return __builtin_amdgcn_perm(ub.u + 0x8000u, ua.u + 0x8000u, 0x07060302u);
}
static __device__ __forceinline__ unsigned short f2bfru(float x) {
  union { float f; unsigned u; } v; v.f = x;
  return (unsigned short)((v.u + 0x8000u) >> 16);
}
static __device__ __forceinline__ float bflo(unsigned d) {
  union { unsigned u; float f; } v; v.u = d << 16; return v.f;
}
static __device__ __forceinline__ float bfhi(unsigned d) {
  union { unsigned u; float f; } v; v.u = d & 0xffff0000u; return v.f;
}
static __device__ __forceinline__ float wredsum(float x) {
#pragma unroll
  for (int off = 32; off; off >>= 1) x += __shfl_xor(x, off, 64);
  return x;
}

__global__ __launch_bounds__(512, 1) void fused_kernel(
    const float* __restrict__ u, const float* __restrict__ ga,
    const float* __restrict__ gb, const float* __restrict__ gc,
    float* __restrict__ out)
{
  // [0,32768): prep G(128x128 bf16)  -> later 16 R/S slots of 2KB
  // [32768,35072): Xk transpose buf (16 cols x 144B)
  // [35072,35584): phi[128]   [35584,35840): kv[64]
  __shared__ __align__(16) char lds[35840];
  unsigned short* G = (unsigned short*)lds;
  char* Xk  = lds + 32768;
  float* phi = (float*)(lds + 35072);
  float* kv  = (float*)(lds + 35584);

  const int i = blockIdx.x;
  const int h = 8 * (i & 31) + (i >> 5);   // heads 8g..8g+7 -> same XCD
  const int t = threadIdx.x;
  const int w = t >> 6, lane = t & 63;
  const int n16 = lane & 15, quad = lane >> 4;

  // ---------------- prep: two chains on waves 0,1 ----------------
  if (w < 2) {
    const float av = ga[h*KD + lane];
    const float an = av / wredsum(fabsf(av));  // mean(|rowsum|) >> eps: always normalize
    const float cv = gc[h*KD + lane];
    if (w == 1) {
      phi[lane] = cv;                          // phi_p = c.A^p e0 = c_p for p<64
      float g = an;                            // g_64 = A^64 e0 = a_n
      for (int p = 64; p < 128; ++p) {
        G[(64 + lane)*128 + (p - 64)] = f2bfru(g);   // T col m = g_{64+m}
        const float d = wredsum(cv * g);
        if (lane == 0) phi[p] = d;
        const float top = __shfl(g, 63, 64);
        const float gm1 = __shfl_up(g, 1, 64);
        g = (lane > 0 ? gm1 : 0.0f) + an * top;
      }
    } else {
      float v = gb[h*KD + lane];               // v_j = A^j b
      for (int j = 0; j < KD; ++j) {
        const float d = wredsum(cv * v);
        if (lane == 0) kv[j] = d;              // k[j] = c.v_j
        G[(64 + lane)*128 + 64 + (63 - j)] = f2bfru(v);  // V col m = v_{63-m}
        const float top = __shfl(v, 63, 64);
        const float vm1 = __shfl_up(v, 1, 64);
        v = (lane > 0 ? vm1 : 0.0f) + an * top;
      }
    }
  }
  __syncthreads();
  // W block: G[j][i] = phi[j+1+i];  Toeplitz: G[j][64+m] = (m<=j)? k[j-m] : 0
  for (int idx = t; idx < 4096; idx += 512) {
    const int j = idx >> 6, ii = idx & 63;
    G[j*128 + ii] = f2bfru(phi[j + 1 + ii]);
  }
  for (int idx = t; idx < 4096; idx += 512) {
    const int j = idx >> 6, m = idx & 63;
    G[j*128 + 64 + m] = (m <= j) ? f2bfru(kv[j - m]) : (unsigned short)0;
  }
  __syncthreads();

  // ---------------- extract A-fragments (32 short8 = 128 VGPR) ----------------
  short8 Aw[4][2], Ap[4][2], Av[4][2], At[4][2];
#pragma unroll
  for (int rt = 0; rt < 4; ++rt)
#pragma unroll
    for (int kt = 0; kt < 2; ++kt) {
      Aw[rt][kt] = *(const short8*)(G + (16*rt + n16)*128 +      32*kt + quad*8);
      Ap[rt][kt] = *(const short8*)(G + (16*rt + n16)*128 + 64 + 32*kt + quad*8);
      At[rt][kt] = *(const short8*)(G + (64 + 16*rt + n16)*128 +      32*kt + quad*8);
      Av[rt][kt] = *(const short8*)(G + (64 + 16*rt + n16)*128 + 64 + 32*kt + quad*8);
    }
  __syncthreads();   // G region dead -> becomes R/S slots

  // ---------------- scan over 4 quarters ----------------
  short8 B0 = {0,0,0,0,0,0,0,0};   // S_0 = 0 (B-frag form, wave 0 carries)
  short8 B1 = {0,0,0,0,0,0,0,0};

  const size_t cs = (size_t)(n16 >> 2) * ((size_t)SL * DM) + 4*h + (n16 & 3);
  const float* up = u + cs;
  float*       op = out + cs;

#pragma unroll 1
  for (int Q = 0; Q < 4; ++Q) {
    const int q0 = Q * 16;

    // ---- Phase A: each wave: chunks q0+w, q0+w+8 ----
    short8 UB[2][2];
#pragma unroll
    for (int s = 0; s < 2; ++s) {
      const int lq = w + 8*s;
      const int qg = q0 + lq;
      float ur[16];
#pragma unroll
      for (int j = 0; j < 8; ++j) {
        ur[j]     = up[(size_t)(qg*64 +      quad*8 + j) * DM];
        ur[8 + j] = up[(size_t)(qg*64 + 32 + quad*8 + j) * DM];
      }
      union { short8 v; unsigned s4[4]; } b2, b3;
#pragma unroll
      for (int jj = 0; jj < 4; ++jj) {
        b2.s4[jj] = pack_bf16(ur[2*jj],     ur[2*jj + 1]);
        b3.s4[jj] = pack_bf16(ur[8 + 2*jj], ur[8 + 2*jj + 1]);
      }
      UB[s][0] = b2.v; UB[s][1] = b3.v;

      char* slot = lds + lq * 2048;
#pragma unroll
      for (int rt = 0; rt < 4; ++rt) {
        floatx4 r = {0.f, 0.f, 0.f, 0.f};
        r = __builtin_amdgcn_mfma_f32_16x16x32_bf16(Av[rt][0], UB[s][0], r, 0,0,0);
        r = __builtin_amdgcn_mfma_f32_16x16x32_bf16(Av[rt][1], UB[s][1], r, 0,0,0);
        uint2 pk; pk.x = pack_bf16(r[0], r[1]); pk.y = pack_bf16(r[2], r[3]);
        *(uint2*)(slot + rt*512 + lane*8) = pk;
      }
    }
    __syncthreads();   // all R slots of this quarter ready

    // ---- Phase B: wave 0 serial scan; slots become S_q B-frags ----
    if (w == 0) {
#pragma unroll 1
      for (int lq = 0; lq < 16; ++lq) {
        char* slot = lds + lq * 2048;
        uint2 rb[4];
#pragma unroll
        for (int rt = 0; rt < 4; ++rt)
          rb[rt] = *(const uint2*)(slot + rt*512 + lane*8);
        floatx4 Cs[4];
#pragma unroll
        for (int rt = 0; rt < 4; ++rt) {
          Cs[rt][0] = bflo(rb[rt].x); Cs[rt][1] = bfhi(rb[rt].x);
          Cs[rt][2] = bflo(rb[rt].y); Cs[rt][3] = bfhi(rb[rt].y);
        }
        // persist S_q (entering state) over the consumed R slot
        *(short8*)(slot + lane*16)        = B0;
        *(short8*)(slot + 1024 + lane*16) = B1;
        // S' = T@S + R
        floatx4 accS[4];
#pragma unroll
        for (int rt = 0; rt < 4; ++rt) {
          floatx4 a0 = __builtin_amdgcn_mfma_f32_16x16x32_bf16(At[rt][0], B0, Cs[rt], 0,0,0);
          accS[rt]   = __builtin_amdgcn_mfma_f32_16x16x32_bf16(At[rt][1], B1, a0,     0,0,0);
        }
        // C-layout -> bf16 -> Xk [col][row] -> next B-frags
#pragma unroll
        for (int rt = 0; rt < 4; ++rt) {
          uint2 pk;
          pk.x = pack_bf16(accS[rt][0], accS[rt][1]);
          pk.y = pack_bf16(accS[rt][2], accS[rt][3]);
          *(uint2*)(Xk + 144*n16 + 32*rt + 8*quad) = pk;
        }
        B0 = *(const short8*)(Xk + 144*n16 +      16*quad);
        B1 = *(const short8*)(Xk + 144*n16 + 64 + 16*quad);
      }
    }
    __syncthreads();   // S_q frags visible to all waves

    // ---- Phase C: Y = Toep@U + W@S for own chunks ----
#pragma unroll
    for (int s = 0; s < 2; ++s) {
      const int lq = w + 8*s;
      const int qg = q0 + lq;
      const char* slot = lds + lq * 2048;
      const short8 S0 = *(const short8*)(slot + lane*16);
      const short8 S1 = *(const short8*)(slot + 1024 + lane*16);
#pragma unroll
      for (int rt = 0; rt < 4; ++rt) {
        floatx4 ty = {0.f, 0.f, 0.f, 0.f};
        ty = __builtin_amdgcn_mfma_f32_16x16x32_bf16(Ap[rt][0], UB[s][0], ty, 0,0,0);
        ty = __builtin_amdgcn_mfma_f32_16x16x32_bf16(Ap[rt][1], UB[s][1], ty, 0,0,0);
        ty = __builtin_amdgcn_mfma_f32_16x16x32_bf16(Aw[rt][0], S0,       ty, 0,0,0);
        ty = __builtin_amdgcn_mfma_f32_16x16x32_bf16(Aw[rt][1], S1,       ty, 0,0,0);
        const size_t rbase = (size_t)(qg*64 + 16*rt + 4*quad);
#pragma unroll
        for (int r = 0; r < 4; ++r) op[(rbase + r) * DM] = ty[r];
      }
    }
    __syncthreads();   // slots dead before next quarter's Phase A
  }
}

// ---------------------------------------------------------------- launch --
extern "C" void kernel_launch(void* const* d_in, const int* in_sizes, int n_in,
                              void* d_out, int out_size, void* d_ws, size_t ws_size,
                              hipStream_t stream)
{
  const float* u = (const float*)d_in[0];
  const float* a = (const float*)d_in[1];
  const float* b = (const float*)d_in[2];
  const float* c = (const float*)d_in[3];
  float* out = (float*)d_out;
  (void)d_ws; (void)ws_size; (void)in_sizes; (void)n_in; (void)out_size;

  fused_kernel<<<NKH, 512, 0, stream>>>(u, a, b, c, out);
}